// Round 2
// baseline (191.188 us; speedup 1.0000x reference)
//
#include <hip/hip_runtime.h>

// out[b,o,h,w] = sum_{c,k} (coef[k]/12.5) * rint( sum_j (12.5*w[k,c,o,j])*x_j + 12.5*b[k,c,o] )
// Pure fp32 VALU problem (no fp32 MFMA on CDNA4; rint sits between the 9-tap conv and the c-sum).

#define NB     8    // weight bits
#define NC     32   // input channels
#define NO     32   // out channels
#define NH     64
#define NW     64
#define NBATCH 8
#define FSTRIDE 12  // padded filter stride in dwords (9 taps + bias + 2 pad) -> 48B, 16B aligned

// Repack + pre-scale weights into [c:32][og:8][k:8][oi:4][12] layout.
// wq[idx*12 + j] = 12.5*w[k][c*32+og*4+oi][j] (j<9), [9] = 12.5*bias
__global__ void prep_wq(const float* __restrict__ w, const float* __restrict__ bias,
                        float* __restrict__ wq) {
    int idx = blockIdx.x * 256 + threadIdx.x;        // idx = ((c*8+og)*8+k)*4+oi
    if (idx >= NC * NO * NB) return;
    int oi = idx & 3;
    int k  = (idx >> 2) & 7;
    int og = (idx >> 5) & 7;
    int c  = idx >> 8;
    int ch = c * NO + og * 4 + oi;                   // channel in original [k][1024] layout
    const float* ws = w + ((size_t)k * (NC * NO) + ch) * 9;
    float* dst = wq + (size_t)idx * FSTRIDE;
#pragma unroll
    for (int j = 0; j < 9; ++j) dst[j] = 12.5f * ws[j];
    dst[9] = 12.5f * bias[k * (NC * NO) + ch];
}

// Wave = (b, og, pair of output rows h0,h0+1). lane = w column (64 wide).
// Block = 4 waves = 8 consecutive rows, same og. Grid (8 og, 8 hblk, 8 b) = 512 blocks.
__global__ __launch_bounds__(256, 2) void demolition_conv(
        const float* __restrict__ x, const float* __restrict__ wq,
        float* __restrict__ out) {
    const int w    = threadIdx.x & 63;
    const int wave = threadIdx.x >> 6;
    const int og   = blockIdx.x;                     // 0..7
    const int h0   = blockIdx.y * 8 + wave * 2;      // 0,2,...,62
    const int b    = blockIdx.z;

    // coef[k]/12.5
    const float ckq[8] = {
        -128.f / 127.f / 12.5f,  1.f / 127.f / 12.5f,  2.f / 127.f / 12.5f,
           4.f / 127.f / 12.5f,  8.f / 127.f / 12.5f, 16.f / 127.f / 12.5f,
          32.f / 127.f / 12.5f, 64.f / 127.f / 12.5f };

    float acc[4][2];
#pragma unroll
    for (int oi = 0; oi < 4; ++oi) { acc[oi][0] = 0.f; acc[oi][1] = 0.f; }

    const bool okL = (w > 0), okR = (w < NW - 1);
    const int  offL = okL ? -1 : 0;
    const int  offR = okR ?  1 : 0;
    const bool top = (h0 > 0);          // row h0-1 valid (wave-uniform)
    const bool bot = (h0 < NH - 2);     // row h0+2 valid

    // three per-lane base pointers (center, left-neighbor, right-neighbor), incremented per c
    const float* xc = x + ((size_t)b * NC * NH + h0) * NW + w;
    const float* xl = xc + offL;
    const float* xr = xc + offR;
    const float* wf = wq + og * (NB * 4 * FSTRIDE);  // [c=0][og] base; +3072 dwords per c

    for (int c = 0; c < NC; ++c, xc += NH * NW, xl += NH * NW, xr += NH * NW, wf += 8 * NB * 4 * FSTRIDE) {
        // input rows h0-1 .. h0+2, each [L, C, R]
        float r0[3], r1[3], r2[3], r3[3];
        r1[1] = xc[0];
        r1[0] = okL ? xl[0] : 0.f;
        r1[2] = okR ? xr[0] : 0.f;
        r2[1] = xc[NW];
        r2[0] = okL ? xl[NW] : 0.f;
        r2[2] = okR ? xr[NW] : 0.f;
        if (top) {
            r0[1] = xc[-NW];
            r0[0] = okL ? xl[-NW] : 0.f;
            r0[2] = okR ? xr[-NW] : 0.f;
        } else { r0[0] = r0[1] = r0[2] = 0.f; }
        if (bot) {
            r3[1] = xc[2 * NW];
            r3[0] = okL ? xl[2 * NW] : 0.f;
            r3[2] = okR ? xr[2 * NW] : 0.f;
        } else { r3[0] = r3[1] = r3[2] = 0.f; }

#pragma unroll
        for (int k = 0; k < NB; ++k) {
#pragma unroll
            for (int oi = 0; oi < 4; ++oi) {
                const float* f = wf + (k * 4 + oi) * FSTRIDE;   // compile-time imm offsets
                const float4 A = *reinterpret_cast<const float4*>(f);
                const float4 Bq = *reinterpret_cast<const float4*>(f + 4);
                const float2 Cq = *reinterpret_cast<const float2*>(f + 8);
                // output row h0 uses rows r0,r1,r2 ; row h0+1 uses r1,r2,r3
                float s0 = Cq.y, s1 = Cq.y;                     // pre-scaled bias
                s0 = fmaf(A.x,  r0[0], s0);  s1 = fmaf(A.x,  r1[0], s1);
                s0 = fmaf(A.y,  r0[1], s0);  s1 = fmaf(A.y,  r1[1], s1);
                s0 = fmaf(A.z,  r0[2], s0);  s1 = fmaf(A.z,  r1[2], s1);
                s0 = fmaf(A.w,  r1[0], s0);  s1 = fmaf(A.w,  r2[0], s1);
                s0 = fmaf(Bq.x, r1[1], s0);  s1 = fmaf(Bq.x, r2[1], s1);
                s0 = fmaf(Bq.y, r1[2], s0);  s1 = fmaf(Bq.y, r2[2], s1);
                s0 = fmaf(Bq.z, r2[0], s0);  s1 = fmaf(Bq.z, r3[0], s1);
                s0 = fmaf(Bq.w, r2[1], s0);  s1 = fmaf(Bq.w, r3[1], s1);
                s0 = fmaf(Cq.x, r2[2], s0);  s1 = fmaf(Cq.x, r3[2], s1);
                acc[oi][0] = fmaf(ckq[k], rintf(s0), acc[oi][0]);
                acc[oi][1] = fmaf(ckq[k], rintf(s1), acc[oi][1]);
            }
        }
    }

    float* op = out + (((size_t)b * NO + og * 4) * NH + h0) * NW + w;
#pragma unroll
    for (int oi = 0; oi < 4; ++oi) {
        op[(size_t)oi * NH * NW]      = acc[oi][0];
        op[(size_t)oi * NH * NW + NW] = acc[oi][1];
    }
}

extern "C" void kernel_launch(void* const* d_in, const int* in_sizes, int n_in,
                              void* d_out, int out_size, void* d_ws, size_t ws_size,
                              hipStream_t stream) {
    const float* x    = (const float*)d_in[0];   // [8,32,64,64]
    const float* wt   = (const float*)d_in[1];   // [8,1024,1,3,3]
    const float* bias = (const float*)d_in[2];   // [8,1024]
    float* out = (float*)d_out;                  // [8,32,64,64]
    float* wq  = (float*)d_ws;                   // 8192 * 12 floats = 384 KiB

    prep_wq<<<(NC * NO * NB + 255) / 256, 256, 0, stream>>>(wt, bias, wq);

    dim3 grid(NO / 4, NH / 8, NBATCH);           // (og, hblk, b) = (8,8,8)
    demolition_conv<<<grid, 256, 0, stream>>>(x, wq, out);
}

// Round 3
// 177.393 us; speedup vs baseline: 1.0778x; 1.0778x over previous
//
#include <hip/hip_runtime.h>

// out[b,o,h,w] = sum_{c,k} (coef[k]/12.5) * rint( sum_j (12.5*w[k,c,o,j])*x_j + 12.5*b[k,c,o] )
// Pure fp32 VALU problem. Latency-bound at low occupancy -> max TLP (32 waves/CU)
// + 2-deep x-load pipeline. Weights on the scalar path (wave-uniform).

#define NB     8
#define NC     32
#define NO     32
#define NH     64
#define NW     64
#define NBATCH 8
#define FSTRIDE 12                      // 9 taps + bias + 2 pad
#define PLANE  (NH * NW)
#define WSTEP  (8 * NB * 4 * FSTRIDE)   // dwords per c step in wq = 3072
#define CHALF  16                       // channels per wave (c split across 2 waves)

// Repack + pre-scale: wq[(((c*8+og)*8+k)*4+oi)*12 + j] = 12.5*w[k][c*32+og*4+oi][j], [9]=12.5*bias
__global__ void prep_wq(const float* __restrict__ w, const float* __restrict__ bias,
                        float* __restrict__ wq) {
    int idx = blockIdx.x * 256 + threadIdx.x;        // idx = ((c*8+og)*8+k)*4+oi
    if (idx >= NC * NO * NB) return;
    int oi = idx & 3;
    int k  = (idx >> 2) & 7;
    int og = (idx >> 5) & 7;
    int c  = idx >> 8;
    int ch = c * NO + og * 4 + oi;
    const float* ws = w + ((size_t)k * (NC * NO) + ch) * 9;
    float* dst = wq + (size_t)idx * FSTRIDE;
#pragma unroll
    for (int j = 0; j < 9; ++j) dst[j] = 12.5f * ws[j];
    dst[9] = 12.5f * bias[k * (NC * NO) + ch];
}

// Wave = (b, og, h, c-half). Block = 4 waves = 2 rows x 2 c-halves, same og.
// Grid (32 hpair, 8 og, 8 b) = 2048 blocks -> 8 blocks/CU = 32 waves/CU.
__global__ __launch_bounds__(256, 8) void demolition_conv(
        const float* __restrict__ x, const float* __restrict__ wq,
        float* __restrict__ out) {
    const int w     = threadIdx.x & 63;
    const int wave  = threadIdx.x >> 6;
    const int chalf = wave & 1;          // which c-half this wave reduces
    const int hsub  = wave >> 1;         // row within the pair
    const int hp    = blockIdx.x;        // 0..31
    const int og    = blockIdx.y;        // 0..7
    const int b     = blockIdx.z;
    const int h     = hp * 2 + hsub;

    const float ckq[8] = {
        -128.f / 127.f / 12.5f,  1.f / 127.f / 12.5f,  2.f / 127.f / 12.5f,
           4.f / 127.f / 12.5f,  8.f / 127.f / 12.5f, 16.f / 127.f / 12.5f,
          32.f / 127.f / 12.5f, 64.f / 127.f / 12.5f };

    float acc[4] = {0.f, 0.f, 0.f, 0.f};

    const bool okL = (w > 0), okR = (w < NW - 1);
    const int  offL = okL ? -1 : 0;
    const int  offR = okR ?  1 : 0;
    const bool rm = (h > 0), rp = (h < NH - 1);     // wave-uniform

    const int c0 = chalf * CHALF;
    const float* xc = x + (((size_t)b * NC + c0) * NH + h) * NW + w;
    const float* xl = xc + offL;
    const float* xr = xc + offR;
    int woff = (c0 * 8 + og) * (NB * 4 * FSTRIDE);

    float bufA[9], bufB[9];

    auto loadx = [&](float* r) {
        r[4] = xc[0];
        r[3] = okL ? xl[0] : 0.f;
        r[5] = okR ? xr[0] : 0.f;
        if (rm) {
            r[1] = xc[-NW];
            r[0] = okL ? xl[-NW] : 0.f;
            r[2] = okR ? xr[-NW] : 0.f;
        } else { r[0] = r[1] = r[2] = 0.f; }
        if (rp) {
            r[7] = xc[NW];
            r[6] = okL ? xl[NW] : 0.f;
            r[8] = okR ? xr[NW] : 0.f;
        } else { r[6] = r[7] = r[8] = 0.f; }
        xc += PLANE; xl += PLANE; xr += PLANE;
    };

    auto compute = [&](const float* xv) {
        const float* wp = wq + __builtin_amdgcn_readfirstlane(woff);
        woff += WSTEP;
#pragma unroll
        for (int oi = 0; oi < 4; ++oi) {
#pragma unroll
            for (int k = 0; k < NB; ++k) {
                const float* f = wp + (k * 4 + oi) * FSTRIDE;   // imm offsets off scalar base
                float s = f[9];
#pragma unroll
                for (int j = 0; j < 9; ++j) s = fmaf(f[j], xv[j], s);
                acc[oi] = fmaf(ckq[k], rintf(s), acc[oi]);
            }
        }
    };

    // 2-deep software pipeline over 16 channels
    loadx(bufA);                         // c0
#pragma unroll 1
    for (int i = 0; i < CHALF - 2; i += 2) {
        loadx(bufB);                     // c_{i+1}
        compute(bufA);                   // c_i
        loadx(bufA);                     // c_{i+2}
        compute(bufB);                   // c_{i+1}
    }
    loadx(bufB);                         // c15
    compute(bufA);                       // c14
    compute(bufB);                       // c15

    // combine the two c-halves in-block
    __shared__ float part[2][4][64];
    if (chalf) {
#pragma unroll
        for (int oi = 0; oi < 4; ++oi) part[hsub][oi][w] = acc[oi];
    }
    __syncthreads();
    if (!chalf) {
        float* op = out + (((size_t)b * NO + og * 4) * NH + h) * NW + w;
#pragma unroll
        for (int oi = 0; oi < 4; ++oi)
            op[(size_t)oi * PLANE] = acc[oi] + part[hsub][oi][w];
    }
}

extern "C" void kernel_launch(void* const* d_in, const int* in_sizes, int n_in,
                              void* d_out, int out_size, void* d_ws, size_t ws_size,
                              hipStream_t stream) {
    const float* x    = (const float*)d_in[0];   // [8,32,64,64]
    const float* wt   = (const float*)d_in[1];   // [8,1024,1,3,3]
    const float* bias = (const float*)d_in[2];   // [8,1024]
    float* out = (float*)d_out;                  // [8,32,64,64]
    float* wq  = (float*)d_ws;                   // 8192*12 floats = 384 KiB

    prep_wq<<<(NC * NO * NB + 255) / 256, 256, 0, stream>>>(wt, bias, wq);

    dim3 grid(NH / 2, NO / 4, NBATCH);           // (hpair, og, b) = (32, 8, 8)
    demolition_conv<<<grid, 256, 0, stream>>>(x, wq, out);
}

// Round 4
// 91.522 us; speedup vs baseline: 2.0890x; 1.9383x over previous
//
#include <hip/hip_runtime.h>

// out[b,o,h,w] = sum_{c,k} (coef[k]/12.5) * rint( sum_j (12.5*w[k,c,o,j])*x_j + 12.5*b[k,c,o] )
// Pure fp32 VALU problem. R4: R1 skeleton + packed fp32 (v_pk_fma_f32) over 2 output rows,
// 2 output channels per wave -> 0.68x instructions, 0.5x scalar weight traffic, same 16 waves/CU.

typedef float v2f __attribute__((ext_vector_type(2)));

#define NB     8
#define NC     32
#define NO     32
#define NH     64
#define NW     64
#define NBATCH 8
#define FST    10                 // filter stride in dwords: 9 taps + bias
#define PLANE  (NH * NW)
#define WCSTEP (16 * 2 * NB * FST)  // dwords per c step in wq = 2560

// wq layout: [c:32][opair:16][oi:2][k:8][10];  value = 12.5*w, [9] = 12.5*bias
__global__ void prep_wq(const float* __restrict__ w, const float* __restrict__ bias,
                        float* __restrict__ wq) {
    int idx = blockIdx.x * 256 + threadIdx.x;      // ((c*16+op)*2+oi)*8+k
    if (idx >= NC * NO * NB) return;
    int k  = idx & 7;
    int oi = (idx >> 3) & 1;
    int op = (idx >> 4) & 15;
    int c  = idx >> 8;
    int ch = c * NO + op * 2 + oi;
    const float* ws = w + ((size_t)k * (NC * NO) + ch) * 9;
    float* dst = wq + (size_t)idx * FST;
#pragma unroll
    for (int j = 0; j < 9; ++j) dst[j] = 12.5f * ws[j];
    dst[9] = 12.5f * bias[k * (NC * NO) + ch];
}

// Wave = (b, o-pair, row-pair h0,h0+1). lane = w. Block = 4 waves = 8 rows, same o-pair.
// Grid (16, 8, 8) = 1024 blocks = 4096 waves = 16 waves/CU (grid-limited, like R1).
__global__ __launch_bounds__(256, 4) void demolition_conv(
        const float* __restrict__ x, const float* __restrict__ wq,
        float* __restrict__ out) {
    const int w    = threadIdx.x & 63;
    const int wave = threadIdx.x >> 6;
    const int op   = blockIdx.x;                   // 0..15 (o-pair)
    const int h0   = blockIdx.y * 8 + wave * 2;    // 0..62 even
    const int b    = blockIdx.z;

    const float ckq[8] = {
        -128.f / 127.f / 12.5f,  1.f / 127.f / 12.5f,  2.f / 127.f / 12.5f,
           4.f / 127.f / 12.5f,  8.f / 127.f / 12.5f, 16.f / 127.f / 12.5f,
          32.f / 127.f / 12.5f, 64.f / 127.f / 12.5f };

    v2f acc0 = {0.f, 0.f}, acc1 = {0.f, 0.f};      // rows (h0,h0+1) for o=2op, 2op+1

    const bool okL = (w > 0), okR = (w < NW - 1);
    const bool top = (h0 > 0), bot = (h0 < NH - 2);   // wave-uniform

    const float* xc = x + ((size_t)b * NC * NH + h0) * NW + w;
    const float* xl = xc + (okL ? -1 : 0);
    const float* xr = xc + (okR ?  1 : 0);
    int woff = op * (2 * NB * FST);                // c=0 base

    for (int c = 0; c < NC; ++c, xc += PLANE, xl += PLANE, xr += PLANE, woff += WCSTEP) {
        // input rows h0-1 .. h0+2 at cols w-1,w,w+1
        float r0[3], r1[3], r2[3], r3[3];
        r1[1] = xc[0];
        r1[0] = okL ? xl[0] : 0.f;
        r1[2] = okR ? xr[0] : 0.f;
        r2[1] = xc[NW];
        r2[0] = okL ? xl[NW] : 0.f;
        r2[2] = okR ? xr[NW] : 0.f;
        if (top) {
            r0[1] = xc[-NW];
            r0[0] = okL ? xl[-NW] : 0.f;
            r0[2] = okR ? xr[-NW] : 0.f;
        } else { r0[0] = r0[1] = r0[2] = 0.f; }
        if (bot) {
            r3[1] = xc[2 * NW];
            r3[0] = okL ? xl[2 * NW] : 0.f;
            r3[2] = okR ? xr[2 * NW] : 0.f;
        } else { r3[0] = r3[1] = r3[2] = 0.f; }

        // packed taps: t[3r+cc] = { x[h0-1+r], x[h0+r] } at col cc
        v2f t[9];
        t[0].x = r0[0]; t[0].y = r1[0];
        t[1].x = r0[1]; t[1].y = r1[1];
        t[2].x = r0[2]; t[2].y = r1[2];
        t[3].x = r1[0]; t[3].y = r2[0];
        t[4].x = r1[1]; t[4].y = r2[1];
        t[5].x = r1[2]; t[5].y = r2[2];
        t[6].x = r2[0]; t[6].y = r3[0];
        t[7].x = r2[1]; t[7].y = r3[1];
        t[8].x = r2[2]; t[8].y = r3[2];

        const float* wp = wq + __builtin_amdgcn_readfirstlane(woff);
#pragma unroll
        for (int oi = 0; oi < 2; ++oi) {
            v2f a = oi ? acc1 : acc0;
#pragma unroll
            for (int k = 0; k < NB; ++k) {
                const float* f = wp + (oi * NB + k) * FST;  // compile-time imm offsets
                v2f s; s.x = f[9]; s.y = f[9];              // pre-scaled bias (both rows)
#pragma unroll
                for (int j = 0; j < 9; ++j) {
                    v2f wv; wv.x = f[j]; wv.y = f[j];       // uniform splat (op_sel broadcast)
                    s = __builtin_elementwise_fma(wv, t[j], s);
                }
                v2f rr; rr.x = rintf(s.x); rr.y = rintf(s.y);
                v2f cv; cv.x = ckq[k]; cv.y = ckq[k];
                a = __builtin_elementwise_fma(cv, rr, a);
            }
            if (oi) acc1 = a; else acc0 = a;
        }
    }

    float* o0 = out + (((size_t)b * NO + op * 2) * NH + h0) * NW + w;
    o0[0]          = acc0.x;
    o0[NW]         = acc0.y;
    o0[PLANE]      = acc1.x;
    o0[PLANE + NW] = acc1.y;
}

extern "C" void kernel_launch(void* const* d_in, const int* in_sizes, int n_in,
                              void* d_out, int out_size, void* d_ws, size_t ws_size,
                              hipStream_t stream) {
    const float* x    = (const float*)d_in[0];   // [8,32,64,64]
    const float* wt   = (const float*)d_in[1];   // [8,1024,1,3,3]
    const float* bias = (const float*)d_in[2];   // [8,1024]
    float* out = (float*)d_out;                  // [8,32,64,64]
    float* wq  = (float*)d_ws;                   // 8192*10 floats = 320 KiB

    prep_wq<<<(NC * NO * NB + 255) / 256, 256, 0, stream>>>(wt, bias, wq);

    dim3 grid(16, 8, NBATCH);                    // (o-pair, h-block, b)
    demolition_conv<<<grid, 256, 0, stream>>>(x, wq, out);
}

// Round 5
// 79.326 us; speedup vs baseline: 2.4102x; 1.1537x over previous
//
#include <hip/hip_runtime.h>

// out[b,o,h,w] = sum_{c,k} (coef[k]/12.5) * rint( sum_j (12.5*w[k,c,o,j])*x_j + 12.5*b[k,c,o] )
// Pure fp32 VALU problem. R5: R4's packed-fp32 2-row shape, but 1 output channel per wave
// -> 8192 waves = 32 waves/CU (8/SIMD). Latency-hiding via TLP, instruction stream near-minimal.

typedef float v2f __attribute__((ext_vector_type(2)));

#define NB     8
#define NC     32
#define NO     32
#define NH     64
#define NW     64
#define NBATCH 8
#define FST    10                  // 9 taps + bias
#define PLANE  (NH * NW)
#define WCSTEP (NO * NB * FST)     // dwords per c step in wq = 2560

// wq layout: [c:32][o:32][k:8][10]; value = 12.5*w, [9] = 12.5*bias
__global__ void prep_wq(const float* __restrict__ w, const float* __restrict__ bias,
                        float* __restrict__ wq) {
    int idx = blockIdx.x * 256 + threadIdx.x;      // (c*32+o)*8+k
    if (idx >= NC * NO * NB) return;
    int k  = idx & 7;
    int ch = idx >> 3;                             // c*32+o
    const float* ws = w + ((size_t)k * (NC * NO) + ch) * 9;
    float* dst = wq + (size_t)idx * FST;
#pragma unroll
    for (int j = 0; j < 9; ++j) dst[j] = 12.5f * ws[j];
    dst[9] = 12.5f * bias[k * (NC * NO) + ch];
}

// Wave = (b, o, row-pair h0,h0+1). lane = w. Block = 4 waves = 8 rows, same o.
// Grid (32 o, 8 hblk, 8 b) = 2048 blocks = 8192 waves = 32 waves/CU.
__global__ __launch_bounds__(256, 8) void demolition_conv(
        const float* __restrict__ x, const float* __restrict__ wq,
        float* __restrict__ out) {
    const int w    = threadIdx.x & 63;
    const int wave = threadIdx.x >> 6;
    const int o    = blockIdx.x;                   // 0..31
    const int h0   = blockIdx.y * 8 + wave * 2;    // 0..62 even
    const int b    = blockIdx.z;

    const float ckq[8] = {
        -128.f / 127.f / 12.5f,  1.f / 127.f / 12.5f,  2.f / 127.f / 12.5f,
           4.f / 127.f / 12.5f,  8.f / 127.f / 12.5f, 16.f / 127.f / 12.5f,
          32.f / 127.f / 12.5f, 64.f / 127.f / 12.5f };

    v2f acc = {0.f, 0.f};                          // rows (h0, h0+1) for channel o

    const bool okL = (w > 0), okR = (w < NW - 1);
    const bool top = (h0 > 0), bot = (h0 < NH - 2);   // wave-uniform

    const float* xc = x + ((size_t)b * NC * NH + h0) * NW + w;
    const float* xl = xc + (okL ? -1 : 0);
    const float* xr = xc + (okR ?  1 : 0);
    int woff = o * (NB * FST);                     // c=0 base

    for (int c = 0; c < NC; ++c, xc += PLANE, xl += PLANE, xr += PLANE, woff += WCSTEP) {
        // input rows h0-1 .. h0+2 at cols w-1,w,w+1
        float r0[3], r1[3], r2[3], r3[3];
        r1[1] = xc[0];
        r1[0] = okL ? xl[0] : 0.f;
        r1[2] = okR ? xr[0] : 0.f;
        r2[1] = xc[NW];
        r2[0] = okL ? xl[NW] : 0.f;
        r2[2] = okR ? xr[NW] : 0.f;
        if (top) {
            r0[1] = xc[-NW];
            r0[0] = okL ? xl[-NW] : 0.f;
            r0[2] = okR ? xr[-NW] : 0.f;
        } else { r0[0] = r0[1] = r0[2] = 0.f; }
        if (bot) {
            r3[1] = xc[2 * NW];
            r3[0] = okL ? xl[2 * NW] : 0.f;
            r3[2] = okR ? xr[2 * NW] : 0.f;
        } else { r3[0] = r3[1] = r3[2] = 0.f; }

        // packed taps: t[3r+cc] = { x[h0-1+r][cc], x[h0+r][cc] }
        v2f t[9];
        t[0].x = r0[0]; t[0].y = r1[0];
        t[1].x = r0[1]; t[1].y = r1[1];
        t[2].x = r0[2]; t[2].y = r1[2];
        t[3].x = r1[0]; t[3].y = r2[0];
        t[4].x = r1[1]; t[4].y = r2[1];
        t[5].x = r1[2]; t[5].y = r2[2];
        t[6].x = r2[0]; t[6].y = r3[0];
        t[7].x = r2[1]; t[7].y = r3[1];
        t[8].x = r2[2]; t[8].y = r3[2];

        const float* wp = wq + __builtin_amdgcn_readfirstlane(woff);
#pragma unroll
        for (int k = 0; k < NB; ++k) {
            const float* f = wp + k * FST;         // compile-time imm offsets off scalar base
            v2f s; s.x = f[9]; s.y = f[9];         // pre-scaled bias (both rows)
#pragma unroll
            for (int j = 0; j < 9; ++j) {
                v2f wv; wv.x = f[j]; wv.y = f[j];  // uniform splat
                s = __builtin_elementwise_fma(wv, t[j], s);
            }
            v2f rr; rr.x = rintf(s.x); rr.y = rintf(s.y);
            v2f cv; cv.x = ckq[k]; cv.y = ckq[k];
            acc = __builtin_elementwise_fma(cv, rr, acc);
        }
    }

    float* o0 = out + (((size_t)b * NO + o) * NH + h0) * NW + w;
    o0[0]  = acc.x;
    o0[NW] = acc.y;
}

extern "C" void kernel_launch(void* const* d_in, const int* in_sizes, int n_in,
                              void* d_out, int out_size, void* d_ws, size_t ws_size,
                              hipStream_t stream) {
    const float* x    = (const float*)d_in[0];   // [8,32,64,64]
    const float* wt   = (const float*)d_in[1];   // [8,1024,1,3,3]
    const float* bias = (const float*)d_in[2];   // [8,1024]
    float* out = (float*)d_out;                  // [8,32,64,64]
    float* wq  = (float*)d_ws;                   // 8192*10 floats = 320 KiB

    prep_wq<<<(NC * NO * NB + 255) / 256, 256, 0, stream>>>(wt, bias, wq);

    dim3 grid(NO, 8, NBATCH);                    // (o, h-block, b)
    demolition_conv<<<grid, 256, 0, stream>>>(x, wq, out);
}